// Round 5
// baseline (115.897 us; speedup 1.0000x reference)
//
#include <hip/hip_runtime.h>
#include <math.h>

#define BATCH 8
#define NN 2048
#define FF 128

typedef __attribute__((ext_vector_type(4))) float f32x4;
typedef _Float16 half8 __attribute__((ext_vector_type(8)));

__device__ __forceinline__ unsigned short h2u(_Float16 h) {
    return __builtin_bit_cast(unsigned short, h);
}

// ---------------------------------------------------------------------------
// k_h: h = x@W via fp16-split MFMA (xh*Wh + xl*Wh + xh*Wl) with W fragments
// derived IN-REGISTER from fp32 W (W is L1/L2-resident; no prep kernel).
// 1024 blocks x 256 thr = 4 blocks/CU: block = 16 rows x 128 cols; wave =
// 16 rows x 32 cols (2 ntiles). h stored as one fp16 plane in B-frag layout;
// epilogue: factored exponentials Sg/S2g/Eg/E2g.
// Each block also packs 2 adj rows -> transposed bitmask amT[jw][i] (ballot).
// R10 lesson: NO device-scope fences (L2-flush storm, ~300us).
// R11 lesson: NO launch_bounds waves/EU=8 (64-VGPR cap -> accumulator spill).
// ---------------------------------------------------------------------------
__global__ __launch_bounds__(256) void k_h(const float* __restrict__ x,
                                           const int* __restrict__ adj,
                                           const float* __restrict__ W,
                                           const float* __restrict__ a_src,
                                           const float* __restrict__ a_dst,
                                           unsigned short* __restrict__ hF,
                                           float* __restrict__ Eg,  float* __restrict__ E2g,
                                           float* __restrict__ Sg,  float* __restrict__ S2g,
                                           unsigned* __restrict__ amT) {
    __shared__ float sred[4 * 16];
    __shared__ float dred[4 * 16];

    const int t = threadIdx.x;
    const int w = t >> 6, lane = t & 63;
    const int nl = lane & 15, quad = lane >> 4;
    const int row0 = blockIdx.x * 16;
    const int b = row0 >> 11, jloc0 = row0 & 2047;
    const int gr = row0 + nl;
    const int nt0 = w * 2;  // wave's ntiles: nt0, nt0+1

    // ---- adj pack: 2 rows/block; wave -> (row w>>1, seg half w&1) ----
    {
        const int prow = blockIdx.x * 2 + (w >> 1);
        const int* __restrict__ ar = adj + (size_t)prow * NN;
        const int s0 = (w & 1) * 16;
        #pragma unroll
        for (int s = 0; s < 16; ++s) {
            const int seg = s0 + s;
            const unsigned long long m = __ballot(ar[seg * 64 + lane] != 0);
            if (lane == 0)  amT[(size_t)(seg * 2) * NN + prow] = (unsigned)m;
            if (lane == 32) amT[(size_t)(seg * 2 + 1) * NN + prow] = (unsigned)(m >> 32);
        }
    }

    f32x4 acc[2] = {{0.f,0.f,0.f,0.f},{0.f,0.f,0.f,0.f}};

    #pragma unroll
    for (int ks = 0; ks < 4; ++ks) {
        // x A-frags
        const float4 xa = *reinterpret_cast<const float4*>(&x[(size_t)gr * FF + ks * 32 + quad * 8]);
        const float4 xb = *reinterpret_cast<const float4*>(&x[(size_t)gr * FF + ks * 32 + quad * 8 + 4]);
        const float xv[8] = {xa.x, xa.y, xa.z, xa.w, xb.x, xb.y, xb.z, xb.w};
        half8 ah, al;
        #pragma unroll
        for (int i = 0; i < 8; ++i) {
            const _Float16 hh = (_Float16)xv[i];
            ah[i] = hh;
            al[i] = (_Float16)(xv[i] - (float)hh);
        }
        // W B-frags derived in-register: B[k][n], k = ks*32 + quad*8 + j
        #pragma unroll
        for (int nn = 0; nn < 2; ++nn) {
            const float* __restrict__ wp = W + (size_t)(ks * 32 + quad * 8) * FF + (nt0 + nn) * 16 + nl;
            half8 bh, bl;
            #pragma unroll
            for (int j = 0; j < 8; ++j) {
                const float wv = wp[j * FF];
                const _Float16 hh = (_Float16)wv;
                bh[j] = hh;
                bl[j] = (_Float16)(wv - (float)hh);
            }
            acc[nn] = __builtin_amdgcn_mfma_f32_16x16x32_f16(ah, bh, acc[nn], 0, 0, 0);
            acc[nn] = __builtin_amdgcn_mfma_f32_16x16x32_f16(al, bh, acc[nn], 0, 0, 0);
            acc[nn] = __builtin_amdgcn_mfma_f32_16x16x32_f16(ah, bl, acc[nn], 0, 0, 0);
        }
    }

    // ---- h store: fp16 plane, B-frag layout [b][nt][jg][n][u] ----
    const int jloc = jloc0 + quad * 4;
    const int jg = jloc >> 3, u0 = jloc & 7;   // u0 in {0,4}
    #pragma unroll
    for (int nn = 0; nn < 2; ++nn) {
        ushort4 hv;
        hv.x = h2u((_Float16)acc[nn][0]);
        hv.y = h2u((_Float16)acc[nn][1]);
        hv.z = h2u((_Float16)acc[nn][2]);
        hv.w = h2u((_Float16)acc[nn][3]);
        *reinterpret_cast<ushort4*>(&hF[(size_t)b * 262144 + (nt0 + nn) * 32768 + jg * 128 + nl * 8 + u0]) = hv;
    }

    // ---- s_src / s_dst partials over this wave's 32 cols ----
    float as[2], ad[2];
    #pragma unroll
    for (int nn = 0; nn < 2; ++nn) {
        const int col = (nt0 + nn) * 16 + nl;
        as[nn] = a_src[col];
        ad[nn] = a_dst[col];
    }
    #pragma unroll
    for (int r = 0; r < 4; ++r) {
        float sp = acc[0][r] * as[0] + acc[1][r] * as[1];
        float dp = acc[0][r] * ad[0] + acc[1][r] * ad[1];
        #pragma unroll
        for (int off = 8; off >= 1; off >>= 1) {
            sp += __shfl_xor(sp, off, 16);
            dp += __shfl_xor(dp, off, 16);
        }
        if (nl == 0) {
            sred[w * 16 + quad * 4 + r] = sp;
            dred[w * 16 + quad * 4 + r] = dp;
        }
    }
    __syncthreads();
    if (t < 16) {
        const float sp = sred[t] + sred[16 + t] + sred[32 + t] + sred[48 + t];
        const float dp = dred[t] + dred[16 + t] + dred[32 + t] + dred[48 + t];
        const int row = row0 + t;
        Sg[row]  = __expf(sp - 2.f);
        S2g[row] = __expf(0.2f * sp - 2.f);
        Eg[row]  = __expf(dp - 2.f);
        E2g[row] = __expf(0.2f * dp - 2.f);
    }
}

// ---------------------------------------------------------------------------
// k_attn (R16): 64-row i-tiles — halve hF traffic AGAIN (262 -> 131 MB; the
// twice-validated lever). Grid dim3(32,8) x 1024 thr = 16 waves = 1 block/CU
// (same 16 waves/CU as R4's 2x8). p-gen code BYTE-IDENTICAL to R4 (rp now
// spans 64 rows); pA grows to 64x136 (34.8 KB, same stride/banking).
// MFMA side: wave = (ntile w&7, K-half w>>3); each wave loads only its
// K-half's B-frags (2 half8/tt -> block reads hF[b] exactly once), computes
// all 4 mtiles of its ntile (acc[4], 8 MFMA/tt — same per-wave as R4).
// Epilogue: kh0 waves park acc in Opart (LDS aliased onto pA, stride 132,
// fenced by the lred barrier), kh1 adds + normalizes by full-K lred[64],
// writes out directly.
// R14 lesson: barriers neutral at same traffic. R15 lesson: hF L2 traffic is
// THE k_attn lever (-7.6us measured, matching model). R13: one delta/round.
// ---------------------------------------------------------------------------
__global__ __launch_bounds__(1024) void k_attn(const unsigned short* __restrict__ hF,
                                               const unsigned* __restrict__ amT,
                                               const float* __restrict__ Eg,
                                               const float* __restrict__ E2g,
                                               const float* __restrict__ Sg,
                                               const float* __restrict__ S2g,
                                               float* __restrict__ out) {
    __shared__ unsigned short pA[2 * 64 * 136];   // 34.8 KB dbuf; epilogue aliases as Opart
    __shared__ float lred[64];

    const int t = threadIdx.x;
    const int b = blockIdx.y;
    const int i0 = blockIdx.x * 64;

    // ---- p-gen ids: thread = 1 row x 8 j (identical to R4; 64 rows now) ----
    const int rp = t >> 4, j8 = t & 15;
    const float Si  = Sg[(size_t)b * NN + i0 + rp];
    const float S2i = S2g[(size_t)b * NN + i0 + rp];
    const int bb = (j8 & 3) * 8;
    const int pwo = rp * 136 + j8 * 8;
    const float* __restrict__ Egb  = Eg  + (size_t)b * NN;
    const float* __restrict__ E2gb = E2g + (size_t)b * NN;
    const unsigned* __restrict__ amb = amT + i0 + rp;

    // ---- MFMA ids: wave = (ntile nt, K-half kh); all 4 mtiles per wave ----
    const int w = t >> 6, lane = t & 63;
    const int nl = lane & 15, quad = lane >> 4;
    const int nt = w & 7, kh = w >> 3;
    const unsigned short* __restrict__ hFb = hF + (size_t)b * 262144;
    const int bofs = nt * 32768 + quad * 128 + nl * 8 + kh * 1024;  // + (kh*2+kkk)*512
    int aofs[4];
    #pragma unroll
    for (int mm = 0; mm < 4; ++mm) aofs[mm] = (mm * 16 + nl) * 136 + quad * 8 + kh * 64;

    f32x4 acc[4] = {{0.f,0.f,0.f,0.f},{0.f,0.f,0.f,0.f},{0.f,0.f,0.f,0.f},{0.f,0.f,0.f,0.f}};
    float la = 0.f;

    for (int tt = 0; tt < 16; ++tt) {
        const int buf = tt & 1;
        const int jofs = tt * 2048;              // 128 j x 16 ushort per 8-j group

        half8 bfr[2];
        #pragma unroll
        for (int kkk = 0; kkk < 2; ++kkk)
            bfr[kkk] = *reinterpret_cast<const half8*>(hFb + bofs + jofs + kkk * 512);

        // ---- p-gen: 1 row x 8 j (E/E2/mask direct from global) ----
        {
            const int jb = tt * 128 + j8 * 8;
            const float4 e0 = *reinterpret_cast<const float4*>(&Egb[jb]);
            const float4 e1 = *reinterpret_cast<const float4*>(&Egb[jb + 4]);
            const float4 f0 = *reinterpret_cast<const float4*>(&E2gb[jb]);
            const float4 f1 = *reinterpret_cast<const float4*>(&E2gb[jb + 4]);
            const unsigned mw = amb[(size_t)(tt * 4 + (j8 >> 2)) * NN];
            const float ejA[8]  = {e0.x, e0.y, e0.z, e0.w, e1.x, e1.y, e1.z, e1.w};
            const float e2A[8]  = {f0.x, f0.y, f0.z, f0.w, f1.x, f1.y, f1.z, f1.w};
            unsigned short hv[8];
            #pragma unroll
            for (int u = 0; u < 8; ++u) {
                const float v = fmaxf(Si * ejA[u], S2i * e2A[u]);
                const float p = ((mw >> (bb + u)) & 1u) ? v : 0.f;
                la += p;
                hv[u] = h2u((_Float16)p);
            }
            *reinterpret_cast<ushort4*>(&pA[buf * 8704 + pwo])     = *reinterpret_cast<ushort4*>(&hv[0]);
            *reinterpret_cast<ushort4*>(&pA[buf * 8704 + pwo + 4]) = *reinterpret_cast<ushort4*>(&hv[4]);
        }

        __syncthreads();

        half8 afr[4][2];
        #pragma unroll
        for (int mm = 0; mm < 4; ++mm)
            #pragma unroll
            for (int kkk = 0; kkk < 2; ++kkk)
                afr[mm][kkk] = *reinterpret_cast<const half8*>(&pA[buf * 8704 + aofs[mm] + kkk * 32]);
        #pragma unroll
        for (int kkk = 0; kkk < 2; ++kkk)
            #pragma unroll
            for (int mm = 0; mm < 4; ++mm)
                acc[mm] = __builtin_amdgcn_mfma_f32_16x16x32_f16(afr[mm][kkk], bfr[kkk], acc[mm], 0, 0, 0);
        // WAR on pA[buf] (rewritten at tt+2) is fenced by the tt+1 barrier:
        // compiler drains lgkmcnt before s_barrier, so this tt's reads are done.
    }

    // ---- full row denominator: reduce la over the 16 threads of the row ----
    #pragma unroll
    for (int off = 8; off >= 1; off >>= 1) la += __shfl_xor(la, off, 16);
    if (j8 == 0) lred[rp] = la;
    __syncthreads();   // also fences the last tt's pA reads before Opart alias writes

    // ---- combine K-halves: kh0 parks partial O in Opart (aliases pA) ----
    float* const Opart = reinterpret_cast<float*>(pA);   // [64][132] stride
    if (kh == 0) {
        #pragma unroll
        for (int mm = 0; mm < 4; ++mm)
            #pragma unroll
            for (int r = 0; r < 4; ++r)
                Opart[(mm * 16 + quad * 4 + r) * 132 + nt * 16 + nl] = acc[mm][r];
    }
    __syncthreads();
    if (kh == 1) {
        float* __restrict__ ob = out + ((size_t)b * NN + i0) * FF;
        #pragma unroll
        for (int mm = 0; mm < 4; ++mm) {
            #pragma unroll
            for (int r = 0; r < 4; ++r) {
                const int lr = mm * 16 + quad * 4 + r;
                const float l = lred[lr];
                const float inv = (l > 0.f) ? 1.f / l : 0.f;   // no-neighbor rows -> 0
                ob[(size_t)lr * FF + nt * 16 + nl] =
                    (acc[mm][r] + Opart[lr * 132 + nt * 16 + nl]) * inv;
            }
        }
    }
}

extern "C" void kernel_launch(void* const* d_in, const int* in_sizes, int n_in,
                              void* d_out, int out_size, void* d_ws, size_t ws_size,
                              hipStream_t stream) {
    const float* x     = (const float*)d_in[0];
    const int*   adj   = (const int*)d_in[1];
    const float* W     = (const float*)d_in[2];
    const float* a_src = (const float*)d_in[3];
    const float* a_dst = (const float*)d_in[4];
    float* out = (float*)d_out;

    unsigned short* hF = (unsigned short*)d_ws;           // 4 MB
    float* Eg  = (float*)(hF + 2097152);                  // 64 KB
    float* E2g = Eg + 16384;                              // 64 KB
    float* Sg  = E2g + 16384;                             // 64 KB
    float* S2g = Sg + 16384;                              // 64 KB
    unsigned* amT = (unsigned*)(S2g + 16384);             // 512 KB

    k_h<<<1024, 256, 0, stream>>>(x, adj, W, a_src, a_dst, hF, Eg, E2g, Sg, S2g, amT);
    k_attn<<<dim3(32, BATCH), 1024, 0, stream>>>(hF, amT, Eg, E2g, Sg, S2g, out);
}

// Round 6
// 109.180 us; speedup vs baseline: 1.0615x; 1.0615x over previous
//
#include <hip/hip_runtime.h>
#include <math.h>

#define BATCH 8
#define NN 2048
#define FF 128

typedef __attribute__((ext_vector_type(4))) float f32x4;
typedef _Float16 half8 __attribute__((ext_vector_type(8)));

__device__ __forceinline__ unsigned short h2u(_Float16 h) {
    return __builtin_bit_cast(unsigned short, h);
}

// ---------------------------------------------------------------------------
// k_h: h = x@W via fp16-split MFMA (xh*Wh + xl*Wh + xh*Wl) with W fragments
// derived IN-REGISTER from fp32 W (W is L1/L2-resident; no prep kernel).
// 1024 blocks x 256 thr = 4 blocks/CU: block = 16 rows x 128 cols; wave =
// 16 rows x 32 cols (2 ntiles). h stored as one fp16 plane in B-frag layout;
// epilogue: factored exponentials Sg/S2g/Eg/E2g.
// Each block also packs 2 adj rows -> transposed bitmask amT[jw][i] (ballot).
// R10 lesson: NO device-scope fences (L2-flush storm, ~300us).
// R11 lesson: NO launch_bounds waves/EU=8 (64-VGPR cap -> accumulator spill).
// ---------------------------------------------------------------------------
__global__ __launch_bounds__(256) void k_h(const float* __restrict__ x,
                                           const int* __restrict__ adj,
                                           const float* __restrict__ W,
                                           const float* __restrict__ a_src,
                                           const float* __restrict__ a_dst,
                                           unsigned short* __restrict__ hF,
                                           float* __restrict__ Eg,  float* __restrict__ E2g,
                                           float* __restrict__ Sg,  float* __restrict__ S2g,
                                           unsigned* __restrict__ amT) {
    __shared__ float sred[4 * 16];
    __shared__ float dred[4 * 16];

    const int t = threadIdx.x;
    const int w = t >> 6, lane = t & 63;
    const int nl = lane & 15, quad = lane >> 4;
    const int row0 = blockIdx.x * 16;
    const int b = row0 >> 11, jloc0 = row0 & 2047;
    const int gr = row0 + nl;
    const int nt0 = w * 2;  // wave's ntiles: nt0, nt0+1

    // ---- adj pack: 2 rows/block; wave -> (row w>>1, seg half w&1) ----
    {
        const int prow = blockIdx.x * 2 + (w >> 1);
        const int* __restrict__ ar = adj + (size_t)prow * NN;
        const int s0 = (w & 1) * 16;
        #pragma unroll
        for (int s = 0; s < 16; ++s) {
            const int seg = s0 + s;
            const unsigned long long m = __ballot(ar[seg * 64 + lane] != 0);
            if (lane == 0)  amT[(size_t)(seg * 2) * NN + prow] = (unsigned)m;
            if (lane == 32) amT[(size_t)(seg * 2 + 1) * NN + prow] = (unsigned)(m >> 32);
        }
    }

    f32x4 acc[2] = {{0.f,0.f,0.f,0.f},{0.f,0.f,0.f,0.f}};

    #pragma unroll
    for (int ks = 0; ks < 4; ++ks) {
        // x A-frags
        const float4 xa = *reinterpret_cast<const float4*>(&x[(size_t)gr * FF + ks * 32 + quad * 8]);
        const float4 xb = *reinterpret_cast<const float4*>(&x[(size_t)gr * FF + ks * 32 + quad * 8 + 4]);
        const float xv[8] = {xa.x, xa.y, xa.z, xa.w, xb.x, xb.y, xb.z, xb.w};
        half8 ah, al;
        #pragma unroll
        for (int i = 0; i < 8; ++i) {
            const _Float16 hh = (_Float16)xv[i];
            ah[i] = hh;
            al[i] = (_Float16)(xv[i] - (float)hh);
        }
        // W B-frags derived in-register: B[k][n], k = ks*32 + quad*8 + j
        #pragma unroll
        for (int nn = 0; nn < 2; ++nn) {
            const float* __restrict__ wp = W + (size_t)(ks * 32 + quad * 8) * FF + (nt0 + nn) * 16 + nl;
            half8 bh, bl;
            #pragma unroll
            for (int j = 0; j < 8; ++j) {
                const float wv = wp[j * FF];
                const _Float16 hh = (_Float16)wv;
                bh[j] = hh;
                bl[j] = (_Float16)(wv - (float)hh);
            }
            acc[nn] = __builtin_amdgcn_mfma_f32_16x16x32_f16(ah, bh, acc[nn], 0, 0, 0);
            acc[nn] = __builtin_amdgcn_mfma_f32_16x16x32_f16(al, bh, acc[nn], 0, 0, 0);
            acc[nn] = __builtin_amdgcn_mfma_f32_16x16x32_f16(ah, bl, acc[nn], 0, 0, 0);
        }
    }

    // ---- h store: fp16 plane, B-frag layout [b][nt][jg][n][u] ----
    const int jloc = jloc0 + quad * 4;
    const int jg = jloc >> 3, u0 = jloc & 7;   // u0 in {0,4}
    #pragma unroll
    for (int nn = 0; nn < 2; ++nn) {
        ushort4 hv;
        hv.x = h2u((_Float16)acc[nn][0]);
        hv.y = h2u((_Float16)acc[nn][1]);
        hv.z = h2u((_Float16)acc[nn][2]);
        hv.w = h2u((_Float16)acc[nn][3]);
        *reinterpret_cast<ushort4*>(&hF[(size_t)b * 262144 + (nt0 + nn) * 32768 + jg * 128 + nl * 8 + u0]) = hv;
    }

    // ---- s_src / s_dst partials over this wave's 32 cols ----
    float as[2], ad[2];
    #pragma unroll
    for (int nn = 0; nn < 2; ++nn) {
        const int col = (nt0 + nn) * 16 + nl;
        as[nn] = a_src[col];
        ad[nn] = a_dst[col];
    }
    #pragma unroll
    for (int r = 0; r < 4; ++r) {
        float sp = acc[0][r] * as[0] + acc[1][r] * as[1];
        float dp = acc[0][r] * ad[0] + acc[1][r] * ad[1];
        #pragma unroll
        for (int off = 8; off >= 1; off >>= 1) {
            sp += __shfl_xor(sp, off, 16);
            dp += __shfl_xor(dp, off, 16);
        }
        if (nl == 0) {
            sred[w * 16 + quad * 4 + r] = sp;
            dred[w * 16 + quad * 4 + r] = dp;
        }
    }
    __syncthreads();
    if (t < 16) {
        const float sp = sred[t] + sred[16 + t] + sred[32 + t] + sred[48 + t];
        const float dp = dred[t] + dred[16 + t] + dred[32 + t] + dred[48 + t];
        const int row = row0 + t;
        Sg[row]  = __expf(sp - 2.f);
        S2g[row] = __expf(0.2f * sp - 2.f);
        Eg[row]  = __expf(dp - 2.f);
        E2g[row] = __expf(0.2f * dp - 2.f);
    }
}

// ---------------------------------------------------------------------------
// k_attn (R17): R4's kernel UNCHANGED except the block->(b,i0) mapping.
// Co-resident blocks on a CU are (bid, bid+256) [256 = #CUs; holds under XCD
// round-robin AND contiguous enumeration]. R4 gave those pairs different
// batches -> two unrelated 512 KB hF streams through the CU. New bijective
// remap lo=bid&255: b=lo>>5, itile=(lo&31)|((bid>>8)<<5) -> pairs share b and
// walk hF[b] in the same tt order -> trailing block's B-frag loads L1-hit,
// halving L2->CU pressure (the R5 target) at ZERO structural cost. Per-batch
// blocks still spread over all 8 XCDs (itile%8) -> hF[b] replicated as now.
// R14: barriers neutral at 2 blocks/CU. R15: hF L2 traffic IS the lever
// (-7.6us). R16: 1 block/CU exposes barrier drains (+6.6us). R13: one delta.
// ---------------------------------------------------------------------------
__global__ __launch_bounds__(512, 4) void k_attn(const unsigned short* __restrict__ hF,
                                                 const unsigned* __restrict__ amT,
                                                 const float* __restrict__ Eg,
                                                 const float* __restrict__ E2g,
                                                 const float* __restrict__ Sg,
                                                 const float* __restrict__ S2g,
                                                 float* __restrict__ out) {
    __shared__ unsigned short pA[2 * 32 * 136];   // 17.4 KB double-buffered
    __shared__ float lred[32];

    const int t = threadIdx.x;
    const int bid = blockIdx.x;
    const int lo = bid & 255;
    const int b = lo >> 5;                               // pairs (bid, bid+256) share b
    const int i0 = (((bid >> 8) << 5) | (lo & 31)) * 32; // i-tiles k and k+32

    // ---- p-gen ids: thread = 1 row x 8 j ----
    const int rp = t >> 4, j8 = t & 15;
    const float Si  = Sg[(size_t)b * NN + i0 + rp];
    const float S2i = S2g[(size_t)b * NN + i0 + rp];
    const int bb = (j8 & 3) * 8;
    const int pwo = rp * 136 + j8 * 8;
    const float* __restrict__ Egb  = Eg  + (size_t)b * NN;
    const float* __restrict__ E2gb = E2g + (size_t)b * NN;
    const unsigned* __restrict__ amb = amT + i0 + rp;

    // ---- MFMA ids: wave w = ntile w, both mtiles ----
    const int w = t >> 6, lane = t & 63;
    const int nl = lane & 15, quad = lane >> 4;
    const unsigned short* __restrict__ hFb = hF + (size_t)b * 262144;
    const int bofs = w * 32768 + quad * 128 + nl * 8;   // single ntile per wave
    int aofs[2];
    #pragma unroll
    for (int mm = 0; mm < 2; ++mm) aofs[mm] = (mm * 16 + nl) * 136 + quad * 8;

    f32x4 acc[2] = {{0.f,0.f,0.f,0.f},{0.f,0.f,0.f,0.f}};   // [mtile]
    float la = 0.f;

    for (int tt = 0; tt < 16; ++tt) {
        const int buf = tt & 1;
        const int jofs = tt * 2048;              // 128 j x 16 ushort per 8-j group

        half8 bfr[4];
        #pragma unroll
        for (int kk = 0; kk < 4; ++kk)
            bfr[kk] = *reinterpret_cast<const half8*>(hFb + bofs + jofs + kk * 512);

        // ---- p-gen: 1 row x 8 j (E/E2/mask direct from global) ----
        {
            const int jb = tt * 128 + j8 * 8;
            const float4 e0 = *reinterpret_cast<const float4*>(&Egb[jb]);
            const float4 e1 = *reinterpret_cast<const float4*>(&Egb[jb + 4]);
            const float4 f0 = *reinterpret_cast<const float4*>(&E2gb[jb]);
            const float4 f1 = *reinterpret_cast<const float4*>(&E2gb[jb + 4]);
            const unsigned mw = amb[(size_t)(tt * 4 + (j8 >> 2)) * NN];
            const float ejA[8]  = {e0.x, e0.y, e0.z, e0.w, e1.x, e1.y, e1.z, e1.w};
            const float e2A[8]  = {f0.x, f0.y, f0.z, f0.w, f1.x, f1.y, f1.z, f1.w};
            unsigned short hv[8];
            #pragma unroll
            for (int u = 0; u < 8; ++u) {
                const float v = fmaxf(Si * ejA[u], S2i * e2A[u]);
                const float p = ((mw >> (bb + u)) & 1u) ? v : 0.f;
                la += p;
                hv[u] = h2u((_Float16)p);
            }
            *reinterpret_cast<ushort4*>(&pA[buf * 4352 + pwo])     = *reinterpret_cast<ushort4*>(&hv[0]);
            *reinterpret_cast<ushort4*>(&pA[buf * 4352 + pwo + 4]) = *reinterpret_cast<ushort4*>(&hv[4]);
        }

        __syncthreads();

        half8 afr[2][4];
        #pragma unroll
        for (int mm = 0; mm < 2; ++mm)
            #pragma unroll
            for (int kk = 0; kk < 4; ++kk)
                afr[mm][kk] = *reinterpret_cast<const half8*>(&pA[buf * 4352 + aofs[mm] + kk * 32]);
        #pragma unroll
        for (int kk = 0; kk < 4; ++kk) {
            acc[0] = __builtin_amdgcn_mfma_f32_16x16x32_f16(afr[0][kk], bfr[kk], acc[0], 0, 0, 0);
            acc[1] = __builtin_amdgcn_mfma_f32_16x16x32_f16(afr[1][kk], bfr[kk], acc[1], 0, 0, 0);
        }
        // WAR on pA[buf] (rewritten at tt+2) is fenced by the tt+1 barrier:
        // compiler drains lgkmcnt before s_barrier, so this tt's reads are done.
    }

    // ---- full row denominator: reduce la over the 16 threads of the row ----
    #pragma unroll
    for (int off = 8; off >= 1; off >>= 1) la += __shfl_xor(la, off, 16);
    if (j8 == 0) lred[rp] = la;
    __syncthreads();

    // ---- normalize + write final output directly ----
    float* __restrict__ ob = out + ((size_t)b * NN + i0) * FF;
    #pragma unroll
    for (int mm = 0; mm < 2; ++mm) {
        #pragma unroll
        for (int r = 0; r < 4; ++r) {
            const int lr = mm * 16 + quad * 4 + r;
            const float l = lred[lr];
            const float inv = (l > 0.f) ? 1.f / l : 0.f;   // no-neighbor rows -> 0
            ob[(size_t)lr * FF + w * 16 + nl] = acc[mm][r] * inv;
        }
    }
}

extern "C" void kernel_launch(void* const* d_in, const int* in_sizes, int n_in,
                              void* d_out, int out_size, void* d_ws, size_t ws_size,
                              hipStream_t stream) {
    const float* x     = (const float*)d_in[0];
    const int*   adj   = (const int*)d_in[1];
    const float* W     = (const float*)d_in[2];
    const float* a_src = (const float*)d_in[3];
    const float* a_dst = (const float*)d_in[4];
    float* out = (float*)d_out;

    unsigned short* hF = (unsigned short*)d_ws;           // 4 MB
    float* Eg  = (float*)(hF + 2097152);                  // 64 KB
    float* E2g = Eg + 16384;                              // 64 KB
    float* Sg  = E2g + 16384;                             // 64 KB
    float* S2g = Sg + 16384;                              // 64 KB
    unsigned* amT = (unsigned*)(S2g + 16384);             // 512 KB

    k_h<<<1024, 256, 0, stream>>>(x, adj, W, a_src, a_dst, hF, Eg, E2g, Sg, S2g, amT);
    k_attn<<<512, 512, 0, stream>>>(hF, amT, Eg, E2g, Sg, S2g, out);
}